// Round 1
// baseline (1580.852 us; speedup 1.0000x reference)
//
#include <hip/hip_runtime.h>
#include <hip/hip_bf16.h>

#define N_H_NODES 50000
#define N_G_NODES 50000
#define N_EDGES   1600000
#define N_GRAPHS  16

typedef __bf16 bf16;
typedef __bf16 bf16x8 __attribute__((ext_vector_type(8)));
typedef __bf16 bf16x4 __attribute__((ext_vector_type(4)));
typedef short  s16x4  __attribute__((ext_vector_type(4)));
typedef float  f32x4  __attribute__((ext_vector_type(4)));

__device__ __forceinline__ bf16 f2b(float f) { return (bf16)f; }

// 16x16x16 bf16 MFMA (K=16, 4 bf16/lane, k = quad*4+j). Its B-fragment layout
// exactly matches the C/D layout of the swapped GEMM1 output, so GEMM1->GEMM2
// needs no LDS and no cross-lane exchange.
__device__ __forceinline__ f32x4 mfma16(s16x4 a, s16x4 b, f32x4 c) {
#if __has_builtin(__builtin_amdgcn_mfma_f32_16x16x16bf16_1k)
    return __builtin_amdgcn_mfma_f32_16x16x16bf16_1k(a, b, c, 0, 0, 0);
#else
    asm("v_mfma_f32_16x16x16_bf16 %0, %1, %2, %0" : "+v"(c) : "v"(a), "v"(b));
    return c;
#endif
}

// ---------------------------------------------------------------------------
// fp32 -> bf16 pre-convert: weights AND x_h (x_h bf16 = 6.4 MB, ~L2-resident,
// halves the random-gather line traffic in the edge kernel).
// ---------------------------------------------------------------------------
__global__ void convert_inputs(const float* __restrict__ W1a, const float* __restrict__ W1b,
                               const float* __restrict__ W2a, const float* __restrict__ W2b,
                               const float* __restrict__ x_h,
                               bf16* __restrict__ o1a, bf16* __restrict__ o1b,
                               bf16* __restrict__ o2a, bf16* __restrict__ o2b,
                               bf16* __restrict__ oxh)
{
    const int i = blockIdx.x * 256 + threadIdx.x;
    if (i < 128 * 128) {
        o1a[i] = f2b(W1a[i]);
        o1b[i] = f2b(W1b[i]);
        o2b[i] = f2b(W2b[i]);
    }
    if (i < 128 * 320) o2a[i] = f2b(W2a[i]);
    if (i < N_H_NODES * 64) oxh[i] = f2b(x_h[i]);   // grid sized to cover exactly
}

// ---------------------------------------------------------------------------
// Counting sort of edges by tgt: histogram -> exclusive scan -> scatter.
// scatter writes int4{e, src[e], tgt[e]} at the sorted position so the edge
// kernel has NO dependent gather chain (one coalesced 16B load per row).
// ---------------------------------------------------------------------------
__global__ void hist_kernel(const int* __restrict__ tgt, int* __restrict__ hist)
{
    const int e = blockIdx.x * 256 + threadIdx.x;
    if (e < N_EDGES) atomicAdd(&hist[tgt[e]], 1);
}

__global__ void scan_cursor(const int* __restrict__ hist, int* __restrict__ cursor)
{
    __shared__ int sums[1024];
    const int t = threadIdx.x;
    const int CH = (N_G_NODES + 1023) / 1024;   // 49
    const int base = t * CH;
    int s = 0;
    for (int i = 0; i < CH; ++i) {
        const int idx = base + i;
        if (idx < N_G_NODES) s += hist[idx];
    }
    sums[t] = s;
    __syncthreads();
    for (int off = 1; off < 1024; off <<= 1) {
        int v = (t >= off) ? sums[t - off] : 0;
        __syncthreads();
        sums[t] += v;
        __syncthreads();
    }
    int run = sums[t] - s;
    for (int i = 0; i < CH; ++i) {
        const int idx = base + i;
        if (idx < N_G_NODES) {
            cursor[idx] = run;
            run += hist[idx];
        }
    }
}

__global__ void scatter_meta(const int* __restrict__ src, const int* __restrict__ tgt,
                             int* __restrict__ cursor, int4* __restrict__ meta)
{
    const int e = blockIdx.x * 256 + threadIdx.x;
    if (e < N_EDGES) {
        const int tg = tgt[e];
        const int p = atomicAdd(&cursor[tg], 1);
        meta[p] = make_int4(e, src[e], tg, 0);   // 16B write; 25.6MB region stays L2-resident
    }
}

// ---------------------------------------------------------------------------
// Edge MLP on tgt-sorted edges, LDS-free GEMM chain.
// GEMM1 (swapped): acc1 = W1a-frag x input-frag = h1^T[feat][edge].
//   acc1[mi][ni] lane layout: feat = ni*16 + quad*4 + r, edge = tile + (lane&15).
// bias+leaky+pack in-register -> pb[mi][kt] are 16x16x16 B-fragments directly
//   (k-tile kt = ni, k = quad*4 + j). No H1 LDS, no barrier between GEMMs.
// GEMM2: h2^T = W1b * h1^T in two 64-feat halves (keeps acc2 at 32 VGPR so
//   the kernel fits 128 VGPR -> 4 blocks/CU).
// LDS: only the h2 reduction chunk (128 x 66 fp32 = 33.8 KB) + tgt[128].
// ---------------------------------------------------------------------------
__global__ __launch_bounds__(256, 4) void edge_mlp_fused(
    const bf16* __restrict__ xh_b, const float* __restrict__ edge_attr,
    const float* __restrict__ b1a, const float* __restrict__ b1b,
    const bf16* __restrict__ W1a, const bf16* __restrict__ W1b,
    const int4* __restrict__ meta, float* __restrict__ a_out)
{
    constexpr int LDH2 = 66;    // fp32 chunk stride (64 + 2 pad): 2-way-free walk reads
    __shared__ __align__(16) float h2s[128 * LDH2];
    __shared__ int tgt_s[128];

    const int t = threadIdx.x;
    const long e0 = (long)blockIdx.x * 128;
    const int wave = t >> 6;
    const int lane = t & 63;
    const int c = lane & 15;
    const int q = lane >> 4;

    if (t < 128) tgt_s[t] = meta[e0 + t].z;

    int eA[2], sA[2];
    #pragma unroll
    for (int mi = 0; mi < 2; ++mi) {
        const int4 m = meta[e0 + wave * 32 + mi * 16 + c];
        eA[mi] = m.x;
        sA[mi] = m.y;
    }

    f32x4 acc1[2][8];
    #pragma unroll
    for (int mi = 0; mi < 2; ++mi)
        #pragma unroll
        for (int ni = 0; ni < 8; ++ni)
            acc1[mi][ni] = (f32x4){0.f, 0.f, 0.f, 0.f};

    // GEMM1 (swapped operands): h1^T = W1a x [x_h[src] | edge_attr]^T, K=128
    #pragma unroll
    for (int ks = 0; ks < 4; ++ks) {
        const int k = ks * 32 + q * 8;
        bf16x8 av[2], bv[8];
        #pragma unroll
        for (int mi = 0; mi < 2; ++mi) {
            if (ks < 2) {
                av[mi] = *(const bf16x8*)(xh_b + (long)sA[mi] * 64 + k);   // one 16B gather
            } else {
                const float* p = edge_attr + (long)eA[mi] * 64 + (k - 64);
                const float4 v0 = *(const float4*)p;
                const float4 v1 = *(const float4*)(p + 4);
                av[mi] = (bf16x8){f2b(v0.x), f2b(v0.y), f2b(v0.z), f2b(v0.w),
                                  f2b(v1.x), f2b(v1.y), f2b(v1.z), f2b(v1.w)};
            }
        }
        #pragma unroll
        for (int ni = 0; ni < 8; ++ni)
            bv[ni] = *(const bf16x8*)(W1a + (ni * 16 + c) * 128 + k);
        #pragma unroll
        for (int mi = 0; mi < 2; ++mi)
            #pragma unroll
            for (int ni = 0; ni < 8; ++ni)
                acc1[mi][ni] = __builtin_amdgcn_mfma_f32_16x16x32_bf16(bv[ni], av[mi], acc1[mi][ni], 0, 0, 0);
    }

    // bias + leaky + pack: acc1[mi][ni] (feats ni*16+q*4+r) -> 16x16x16 B-frag pb[mi][ni]
    s16x4 pb[2][8];
    #pragma unroll
    for (int ni = 0; ni < 8; ++ni) {
        const float4 b4 = *(const float4*)(b1a + ni * 16 + q * 4);
        #pragma unroll
        for (int mi = 0; mi < 2; ++mi) {
            float v0 = acc1[mi][ni][0] + b4.x;
            float v1 = acc1[mi][ni][1] + b4.y;
            float v2 = acc1[mi][ni][2] + b4.z;
            float v3 = acc1[mi][ni][3] + b4.w;
            v0 = (v0 >= 0.f) ? v0 : 0.1f * v0;
            v1 = (v1 >= 0.f) ? v1 : 0.1f * v1;
            v2 = (v2 >= 0.f) ? v2 : 0.1f * v2;
            v3 = (v3 >= 0.f) ? v3 : 0.1f * v3;
            bf16x4 bt = (bf16x4){f2b(v0), f2b(v1), f2b(v2), f2b(v3)};
            pb[mi][ni] = *(s16x4*)&bt;
        }
    }

    // GEMM2 + segmented reduction, two 64-output-feat halves.
    for (int h = 0; h < 2; ++h) {
        f32x4 acc2[2][4];
        #pragma unroll
        for (int mi = 0; mi < 2; ++mi)
            #pragma unroll
            for (int no = 0; no < 4; ++no)
                acc2[mi][no] = (f32x4){0.f, 0.f, 0.f, 0.f};
        #pragma unroll
        for (int kt = 0; kt < 8; ++kt) {
            s16x4 wv[4];
            #pragma unroll
            for (int no = 0; no < 4; ++no)
                wv[no] = *(const s16x4*)(W1b + (h * 64 + no * 16 + c) * 128 + kt * 16 + q * 4);
            #pragma unroll
            for (int mi = 0; mi < 2; ++mi)
                #pragma unroll
                for (int no = 0; no < 4; ++no)
                    acc2[mi][no] = mfma16(wv[no], pb[mi][kt], acc2[mi][no]);
        }
        __syncthreads();   // previous walk (or tgt_s fill) done; h2s free
        #pragma unroll
        for (int no = 0; no < 4; ++no) {
            const float4 b4 = *(const float4*)(b1b + h * 64 + no * 16 + q * 4);
            #pragma unroll
            for (int mi = 0; mi < 2; ++mi) {
                // h2s[edge_row][feat]: 4 consecutive floats per lane (8B-aligned)
                float* dst = &h2s[(wave * 32 + mi * 16 + c) * LDH2 + no * 16 + q * 4];
                dst[0] = acc2[mi][no][0] + b4.x;
                dst[1] = acc2[mi][no][1] + b4.y;
                dst[2] = acc2[mi][no][2] + b4.z;
                dst[3] = acc2[mi][no][3] + b4.w;
            }
        }
        __syncthreads();
        // 256 threads = 64 cols x 4 row-quarters; wave == quarter -> wave-uniform
        // tgt-run walk, 64-wide coalesced atomic flushes (~1k atomics/block).
        {
            const int cc = t & 63;
            const int qq = t >> 6;
            float s = 0.f;
            int cur = tgt_s[qq * 32];
            #pragma unroll 8
            for (int i = 0; i < 32; ++i) {
                const int tg = tgt_s[qq * 32 + i];
                if (tg != cur) {
                    atomicAdd(&a_out[(long)cur * 128 + h * 64 + cc], s);
                    s = 0.f;
                    cur = tg;
                }
                s += h2s[(qq * 32 + i) * LDH2 + cc];
            }
            atomicAdd(&a_out[(long)cur * 128 + h * 64 + cc], s);
        }
    }
}

// ---------------------------------------------------------------------------
// Node MLP: unchanged (not the bottleneck this round)
// ---------------------------------------------------------------------------
__global__ __launch_bounds__(256, 4) void node_mlp2(
    const float* __restrict__ x_g, const float* __restrict__ u,
    const float* __restrict__ b2a, const float* __restrict__ b2b,
    const bf16* __restrict__ W2a, const bf16* __restrict__ W2b,
    const int* __restrict__ batch_g, const float* __restrict__ a_in,
    float* __restrict__ out)
{
    constexpr int LDH = 136;
    __shared__ __align__(16) bf16 H1[128 * LDH];

    const int t = threadIdx.x;
    const int n0 = blockIdx.x * 128;
    const int wave = t >> 6;
    const int lane = t & 63;
    const int col  = lane & 15;
    const int quad = lane >> 4;

    int grow[2];
    int bg[2];
    #pragma unroll
    for (int mi = 0; mi < 2; ++mi) {
        const int r = n0 + wave * 32 + mi * 16 + col;
        grow[mi] = min(r, N_G_NODES - 1);
        bg[mi] = batch_g[grow[mi]];
    }

    f32x4 acc[2][8];
    #pragma unroll
    for (int mi = 0; mi < 2; ++mi)
        #pragma unroll
        for (int ni = 0; ni < 8; ++ni)
            acc[mi][ni] = (f32x4){0.f, 0.f, 0.f, 0.f};

    // GEMM1: K=320
    #pragma unroll
    for (int ks = 0; ks < 10; ++ks) {
        const int k = ks * 32 + quad * 8;
        bf16x8 av[2], bv[8];
        #pragma unroll
        for (int mi = 0; mi < 2; ++mi) {
            const float* p;
            if (k < 128)      p = x_g  + (long)grow[mi] * 128 + k;
            else if (k < 256) p = a_in + (long)grow[mi] * 128 + (k - 128);
            else              p = u + bg[mi] * 64 + (k - 256);
            const float4 v0 = *(const float4*)p;
            const float4 v1 = *(const float4*)(p + 4);
            av[mi] = (bf16x8){f2b(v0.x), f2b(v0.y), f2b(v0.z), f2b(v0.w),
                              f2b(v1.x), f2b(v1.y), f2b(v1.z), f2b(v1.w)};
        }
        #pragma unroll
        for (int ni = 0; ni < 8; ++ni)
            bv[ni] = *(const bf16x8*)(W2a + (long)(ni * 16 + col) * 320 + k);
        #pragma unroll
        for (int mi = 0; mi < 2; ++mi)
            #pragma unroll
            for (int ni = 0; ni < 8; ++ni)
                acc[mi][ni] = __builtin_amdgcn_mfma_f32_16x16x32_bf16(av[mi], bv[ni], acc[mi][ni], 0, 0, 0);
    }

    // epilogue 1 -> H1 (bf16)
    #pragma unroll
    for (int ni = 0; ni < 8; ++ni) {
        const float bias = b2a[ni * 16 + col];
        #pragma unroll
        for (int mi = 0; mi < 2; ++mi) {
            #pragma unroll
            for (int r = 0; r < 4; ++r) {
                float v = acc[mi][ni][r] + bias;
                v = (v >= 0.f) ? v : 0.1f * v;
                const int row = wave * 32 + mi * 16 + quad * 4 + r;
                H1[row * LDH + ni * 16 + col] = f2b(v);
            }
        }
    }
    __syncthreads();

    // GEMM2: K=128
    #pragma unroll
    for (int mi = 0; mi < 2; ++mi)
        #pragma unroll
        for (int ni = 0; ni < 8; ++ni)
            acc[mi][ni] = (f32x4){0.f, 0.f, 0.f, 0.f};
    #pragma unroll
    for (int ks = 0; ks < 4; ++ks) {
        bf16x8 av[2], bv[8];
        #pragma unroll
        for (int mi = 0; mi < 2; ++mi)
            av[mi] = *(const bf16x8*)(&H1[(wave * 32 + mi * 16 + col) * LDH + ks * 32 + quad * 8]);
        #pragma unroll
        for (int ni = 0; ni < 8; ++ni)
            bv[ni] = *(const bf16x8*)(W2b + (long)(ni * 16 + col) * 128 + ks * 32 + quad * 8);
        #pragma unroll
        for (int mi = 0; mi < 2; ++mi)
            #pragma unroll
            for (int ni = 0; ni < 8; ++ni)
                acc[mi][ni] = __builtin_amdgcn_mfma_f32_16x16x32_bf16(av[mi], bv[ni], acc[mi][ni], 0, 0, 0);
    }

    // epilogue 2: bias + store (row-guarded)
    #pragma unroll
    for (int ni = 0; ni < 8; ++ni) {
        const float bias = b2b[ni * 16 + col];
        #pragma unroll
        for (int mi = 0; mi < 2; ++mi) {
            #pragma unroll
            for (int r = 0; r < 4; ++r) {
                const int row = wave * 32 + mi * 16 + quad * 4 + r;
                const int g = n0 + row;
                if (g < N_G_NODES)
                    out[(long)g * 128 + ni * 16 + col] = acc[mi][ni][r] + bias;
            }
        }
    }
}

// ---------------------------------------------------------------------------
extern "C" void kernel_launch(void* const* d_in, const int* in_sizes, int n_in,
                              void* d_out, int out_size, void* d_ws, size_t ws_size,
                              hipStream_t stream)
{
    const float* x_h  = (const float*)d_in[0];
    const float* x_g  = (const float*)d_in[1];
    const float* edge_attr = (const float*)d_in[2];
    const float* u    = (const float*)d_in[3];
    const float* W1a  = (const float*)d_in[4];
    const float* b1a  = (const float*)d_in[5];
    const float* W1b  = (const float*)d_in[6];
    const float* b1b  = (const float*)d_in[7];
    const float* W2a  = (const float*)d_in[8];
    const float* b2a  = (const float*)d_in[9];
    const float* W2b  = (const float*)d_in[10];
    const float* b2b  = (const float*)d_in[11];
    const int* edge_index = (const int*)d_in[12];   // [2, E]
    const int* batch_g    = (const int*)d_in[13];
    const int* src = edge_index;
    const int* tgt = edge_index + N_EDGES;

    char* ws = (char*)d_ws;
    size_t off = 0;
    float* a_acc = (float*)(ws + off); off += (size_t)N_G_NODES * 128 * sizeof(float);
    bf16* w1a = (bf16*)(ws + off); off += (size_t)128 * 128 * sizeof(bf16);
    bf16* w1b = (bf16*)(ws + off); off += (size_t)128 * 128 * sizeof(bf16);
    bf16* w2a = (bf16*)(ws + off); off += (size_t)128 * 320 * sizeof(bf16);
    bf16* w2b = (bf16*)(ws + off); off += (size_t)128 * 128 * sizeof(bf16);
    bf16* xh_b = (bf16*)(ws + off); off += (size_t)N_H_NODES * 64 * sizeof(bf16);
    int* hist   = (int*)(ws + off); off += (size_t)N_G_NODES * sizeof(int);
    int* cursor = (int*)(ws + off); off += (size_t)N_G_NODES * sizeof(int);
    int4* meta  = (int4*)(ws + off); off += (size_t)N_EDGES * sizeof(int4);

    hipMemsetAsync(a_acc, 0, (size_t)N_G_NODES * 128 * sizeof(float), stream);
    hipMemsetAsync(hist, 0, (size_t)N_G_NODES * sizeof(int), stream);

    convert_inputs<<<(N_H_NODES * 64) / 256, 256, 0, stream>>>(W1a, W1b, W2a, W2b, x_h,
                                                               w1a, w1b, w2a, w2b, xh_b);
    hist_kernel<<<(N_EDGES + 255) / 256, 256, 0, stream>>>(tgt, hist);
    scan_cursor<<<1, 1024, 0, stream>>>(hist, cursor);
    scatter_meta<<<(N_EDGES + 255) / 256, 256, 0, stream>>>(src, tgt, cursor, meta);
    edge_mlp_fused<<<N_EDGES / 128, 256, 0, stream>>>(xh_b, edge_attr, b1a, b1b,
                                                      w1a, w1b, meta, a_acc);
    node_mlp2<<<(N_G_NODES + 127) / 128, 256, 0, stream>>>(x_g, u, b2a, b2b,
                                                           w2a, w2b, batch_g, a_acc,
                                                           (float*)d_out);
}